// Round 6
// baseline (390.073 us; speedup 1.0000x reference)
//
#include <hip/hip_runtime.h>

typedef __bf16 bf16;
typedef __bf16 bf16x8 __attribute__((ext_vector_type(8)));
typedef float f32x4 __attribute__((ext_vector_type(4)));

#define MFMA16(a,b,c) __builtin_amdgcn_mfma_f32_16x16x32_bf16((a),(b),(c),0,0,0)
#define SBAR() __builtin_amdgcn_s_barrier()
#define SCHED0() __builtin_amdgcn_sched_barrier(0)
#define WAIT_LGKM0() do { asm volatile("s_waitcnt lgkmcnt(0)" ::: "memory"); SCHED0(); } while (0)
#define WAIT_VM0()   do { asm volatile("s_waitcnt vmcnt(0)"   ::: "memory"); SCHED0(); } while (0)

// Shapes (fixed): B=32, N=384, C=768, H=12, Dh=64, mt=128, 2B=64 batches.
// Global inputs/outputs FLOAT32; intermediates bf16.
// Xb (x bf16 [24576][768]) + Wq (qkv_w bf16 [2304][768]) live in d_out scratch.
// ws: Q | K | V | ATT (each 36 MB bf16) = 151 MB; Wp reuses Q after attn.
//
// GEMMs: m201-style 8-phase schedule. 256x256 tile, BK=64, 8 waves (2Mx4N),
// per-wave 128x64. Double-buffered LDS (128 KB). Per K-tile: 4 phases, each
// {stage 2 gload_lds of tile t+1 || ds_read quadrant frags} -> s_barrier ->
// lgkmcnt(0)+sched_barrier -> setprio(1) -> 16 MFMA -> setprio(0) -> s_barrier.
// vmcnt(0) once per tile (phase 3) — loads span the whole tile's compute.
// 8-slot XOR swizzle (slot ^= row&7) on BOTH store-source and read (T2).

__device__ inline void gload16(const bf16* g, bf16* l) {
  __builtin_amdgcn_global_load_lds(
      (const __attribute__((address_space(1))) void*)g,
      (__attribute__((address_space(3))) void*)l, 16, 0, 0);
}

// Stage part p (of 4) of a 256x64 bf16 tile from a row-major [*,768] panel.
// LDS linear dest (wave-uniform base + lane*16B); global column chunk
// pre-swizzled: chunk = (s&7)^(row&7).
__device__ inline void stage_part(const bf16* __restrict__ gsrc,
                                  bf16* lbase, int p, int tid, int wv) {
  int s = p * 512 + tid;                        // 0..2047
  int row = s >> 3;
  int chunk = (s & 7) ^ (row & 7);
  gload16(gsrc + (size_t)row * 768 + chunk * 8,
          lbase + (size_t)(p * 512 + wv * 64) * 8);
}

// Read a 16B MFMA fragment at (row, ksub, lg) from a swizzled 256x64 tile.
__device__ inline bf16x8 frag64(const bf16* buf, int row, int ks, int lg) {
  int slot = ((ks << 2) | lg) ^ (row & 7);
  return *(const bf16x8*)(buf + (size_t)row * 64 + slot * 8);
}

// ---------------------------------------------------------------------------
// convert1: pack xv | xi | qkv_w (f32) -> bf16 into d_out scratch.
// ---------------------------------------------------------------------------
__global__ __launch_bounds__(256) void convert1_kernel(
    const float* __restrict__ xv, const float* __restrict__ xi,
    const float* __restrict__ w, bf16* __restrict__ dst)
{
  const size_t NV = 9437184;     // 12288*768
  const size_t NX = 18874368;    // 2*NV
  const size_t NT = 20643840;    // NX + 1769472 (qkv_w)
  for (size_t i = (size_t)blockIdx.x * 256 + threadIdx.x; i * 8 < NT;
       i += (size_t)gridDim.x * 256) {
    size_t e = i * 8;
    const float* src;
    if (e < NV)      src = xv + e;
    else if (e < NX) src = xi + (e - NV);
    else             src = w + (e - NX);
    f32x4 a = *(const f32x4*)src;
    f32x4 b = *(const f32x4*)(src + 4);
    bf16x8 r;
    r[0] = (bf16)a[0]; r[1] = (bf16)a[1]; r[2] = (bf16)a[2]; r[3] = (bf16)a[3];
    r[4] = (bf16)b[0]; r[5] = (bf16)b[1]; r[6] = (bf16)b[2]; r[7] = (bf16)b[3];
    *(bf16x8*)(dst + e) = r;
  }
}

// convert2: proj_w (f32, 589824) -> bf16 (into dead Q region).
__global__ __launch_bounds__(256) void convert2_kernel(
    const float* __restrict__ w, bf16* __restrict__ dst)
{
  size_t i = (size_t)blockIdx.x * 256 + threadIdx.x;
  size_t e = i * 8;
  if (e >= 589824) return;
  f32x4 a = *(const f32x4*)(w + e);
  f32x4 b = *(const f32x4*)(w + e + 4);
  bf16x8 r;
  r[0] = (bf16)a[0]; r[1] = (bf16)a[1]; r[2] = (bf16)a[2]; r[3] = (bf16)a[3];
  r[4] = (bf16)b[0]; r[5] = (bf16)b[1]; r[6] = (bf16)b[2]; r[7] = (bf16)b[3];
  *(bf16x8*)(dst + e) = r;
}

// ---------------------------------------------------------------------------
// Shared 8-phase K-loop body (qkv + proj). Computes acc[8][4] for one block.
// ---------------------------------------------------------------------------
#define GEMM_8PHASE_LOOP(APANEL, BPANEL)                                        \
  do {                                                                          \
    _Pragma("unroll")                                                           \
    for (int p = 0; p < 4; ++p) {                                               \
      stage_part(APANEL, &As[0][0][0], p, tid, wv);                             \
      stage_part(BPANEL, &Bs[0][0][0], p, tid, wv);                             \
    }                                                                           \
    WAIT_VM0();                                                                 \
    SBAR();                                                                     \
    for (int t = 0; t < 12; ++t) {                                              \
      const bf16* Ab = &As[t & 1][0][0];                                        \
      const bf16* Bb = &Bs[t & 1][0][0];                                        \
      bf16* An = &As[(t + 1) & 1][0][0];                                        \
      bf16* Bn = &Bs[(t + 1) & 1][0][0];                                        \
      const bf16* Xn = (APANEL) + (t + 1) * 64;                                 \
      const bf16* Wn = (BPANEL) + (t + 1) * 64;                                 \
      const bool pf = (t + 1) < 12;                                             \
      bf16x8 bfrag[4][2];                                                       \
      _Pragma("unroll")                                                         \
      for (int p = 0; p < 4; ++p) {                                             \
        if (pf) { stage_part(Xn, An, p, tid, wv); stage_part(Wn, Bn, p, tid, wv); } \
        if (p == 0) {                                                           \
          _Pragma("unroll")                                                     \
          for (int nf = 0; nf < 4; ++nf)                                        \
            _Pragma("unroll")                                                   \
            for (int ks = 0; ks < 2; ++ks)                                      \
              bfrag[nf][ks] = frag64(Bb, wn * 64 + nf * 16 + lr, ks, lg);       \
        }                                                                       \
        bf16x8 af[2][2];                                                        \
        _Pragma("unroll")                                                       \
        for (int i = 0; i < 2; ++i)                                             \
          _Pragma("unroll")                                                     \
          for (int ks = 0; ks < 2; ++ks)                                        \
            af[i][ks] = frag64(Ab, wm * 128 + (p * 2 + i) * 16 + lr, ks, lg);   \
        SBAR();                                                                 \
        WAIT_LGKM0();                                                           \
        __builtin_amdgcn_s_setprio(1);                                          \
        _Pragma("unroll")                                                       \
        for (int i = 0; i < 2; ++i)                                             \
          _Pragma("unroll")                                                     \
          for (int nf = 0; nf < 4; ++nf)                                        \
            _Pragma("unroll")                                                   \
            for (int ks = 0; ks < 2; ++ks)                                      \
              acc[p * 2 + i][nf] = MFMA16(af[i][ks], bfrag[nf][ks], acc[p * 2 + i][nf]); \
        __builtin_amdgcn_s_setprio(0);                                          \
        SCHED0();                                                               \
        if (p == 3) WAIT_VM0();    /* my 8 tile-(t+1) loads have landed */      \
        SBAR();                                                                 \
      }                                                                         \
    }                                                                           \
  } while (0)

// ---------------------------------------------------------------------------
// Kernel 1: QKV projection. 256x256 tile, BK=64, scatter epilogue to Q/K/V.
// ---------------------------------------------------------------------------
__global__ __launch_bounds__(512, 2) void qkv_kernel(
    const bf16* __restrict__ X, const bf16* __restrict__ W,
    bf16* __restrict__ Qo, bf16* __restrict__ Ko, bf16* __restrict__ Vo)
{
  __shared__ bf16 As[2][256][64];
  __shared__ bf16 Bs[2][256][64];
  int bid = blockIdx.x;                    // 864 blocks
  int swz = (bid & 7) * 108 + (bid >> 3);  // XCD-contiguous, bijective (864=8*108)
  const int nt = swz % 9, mt = swz / 9;
  const int m0 = mt * 256, n0 = nt * 256;
  const int tid = threadIdx.x;
  const int lane = tid & 63;
  const int wv = tid >> 6;                 // 0..7
  const int wm = wv >> 2, wn = wv & 3;     // 2x4 wave grid; wave out 128x64
  const int lr = lane & 15, lg = lane >> 4;

  const bf16* Xp = X + (size_t)m0 * 768;
  const bf16* Wp = W + (size_t)n0 * 768;

  f32x4 acc[8][4] = {};

  GEMM_8PHASE_LOOP(Xp, Wp);

#pragma unroll
  for (int mf = 0; mf < 8; ++mf)
#pragma unroll
    for (int nf = 0; nf < 4; ++nf)
#pragma unroll
      for (int r = 0; r < 4; ++r) {
        int m = m0 + wm * 128 + mf * 16 + lg * 4 + r;
        int n = n0 + wn * 64 + nf * 16 + lr;
        int bp = m / 384, tok = m - bp * 384;
        int comp = (n >= 1536) ? 2 : (n >= 768) ? 1 : 0;
        int rem = n - comp * 768;
        int hh = rem >> 6, d = rem & 63;
        size_t addr = (((size_t)bp * 12 + hh) * 384 + tok) * 64 + d;
        float val = acc[mf][nf][r];
        if (comp == 0)      Qo[addr] = (bf16)(val * 0.125f);   // fold 1/sqrt(Dh)
        else if (comp == 1) Ko[addr] = (bf16)val;
        else                Vo[addr] = (bf16)val;
      }
}

// ---------------------------------------------------------------------------
// Kernel 2: attention (unchanged, verified). grid = 64*12*3.
// ---------------------------------------------------------------------------
__global__ __launch_bounds__(256) void attn_kernel(
    const bf16* __restrict__ Q, const bf16* __restrict__ K, const bf16* __restrict__ V,
    bf16* __restrict__ ATT)
{
  __shared__ union {
    bf16 Qs[128][72];
    bf16 Ps[4][32][136];     // per-wave P tile (Qs dead after qf reg-cache)
  } u;
  __shared__ bf16 Ks[128][72];
  __shared__ bf16 VTs[64][136];     // transposed V: [d][token]

  const int bid = blockIdx.x;
  const int qb = bid % 3;
  const int h  = (bid / 3) % 12;
  const int bp = bid / 36;           // b' in [0,64)
  const int tid = threadIdx.x;
  const int lane = tid & 63;
  const int wv = tid >> 6;
  const int lr = lane & 15, lg = lane >> 4;

  const size_t bh384 = ((size_t)bp * 12 + h) * 384;
  const int q0 = qb * 128;

  for (int v = tid; v < 1024; v += 256) {
    int row = v >> 3, cg = (v & 7) * 8;
    *(bf16x8*)(&u.Qs[row][cg]) = *(const bf16x8*)(Q + (bh384 + q0 + row) * 64 + cg);
  }
  __syncthreads();

  bf16x8 qf[2][2];
#pragma unroll
  for (int mf = 0; mf < 2; ++mf)
#pragma unroll
    for (int ks = 0; ks < 2; ++ks)
      qf[mf][ks] = *(const bf16x8*)(&u.Qs[wv * 32 + mf * 16 + lr][ks * 32 + lg * 8]);

  f32x4 O[2][4] = {};
  float runmax[2][4], runsum[2][4];
#pragma unroll
  for (int mf = 0; mf < 2; ++mf)
#pragma unroll
    for (int r = 0; r < 4; ++r) { runmax[mf][r] = -1e30f; runsum[mf][r] = 0.f; }

  const int nchunks = (qb == 0) ? 1 : 4;
  for (int c = 0; c < nchunks; ++c) {
    int src_b, t0;
    if (qb == 0)      { src_b = bp;            t0 = 0; }
    else if (c == 0)  { src_b = bp & 31;       t0 = 0; }          // mt of V batch
    else if (c == 1)  { src_b = (bp & 31)+32;  t0 = 0; }          // mt of I batch
    else              { src_b = bp;            t0 = (c - 1) * 128; } // own s tokens
    const size_t kb = (((size_t)src_b * 12 + h) * 384 + t0) * 64;

    __syncthreads();   // previous chunk fully consumed before restaging
    for (int v = tid; v < 1024; v += 256) {
      int row = v >> 3, cg = (v & 7) * 8;
      *(bf16x8*)(&Ks[row][cg]) = *(const bf16x8*)(K + kb + row * 64 + cg);
      bf16x8 vvld = *(const bf16x8*)(V + kb + row * 64 + cg);
#pragma unroll
      for (int j = 0; j < 8; ++j) VTs[cg + j][row] = vvld[j];
    }
    __syncthreads();

    // S = Q * Kc^T   (scale already folded into Q)
    f32x4 S[2][8] = {};
#pragma unroll
    for (int nf = 0; nf < 8; ++nf) {
#pragma unroll
      for (int ks = 0; ks < 2; ++ks) {
        bf16x8 kf = *(const bf16x8*)(&Ks[nf * 16 + lr][ks * 32 + lg * 8]);
        S[0][nf] = MFMA16(qf[0][ks], kf, S[0][nf]);
        S[1][nf] = MFMA16(qf[1][ks], kf, S[1][nf]);
      }
    }

    // online softmax (row = lg*4 + r within 16-row fragment; 16-lane reduce)
#pragma unroll
    for (int mf = 0; mf < 2; ++mf) {
#pragma unroll
      for (int r = 0; r < 4; ++r) {
        float mx = S[mf][0][r];
#pragma unroll
        for (int nf = 1; nf < 8; ++nf) mx = fmaxf(mx, S[mf][nf][r]);
        mx = fmaxf(mx, __shfl_xor(mx, 1));
        mx = fmaxf(mx, __shfl_xor(mx, 2));
        mx = fmaxf(mx, __shfl_xor(mx, 4));
        mx = fmaxf(mx, __shfl_xor(mx, 8));
        float nm = fmaxf(runmax[mf][r], mx);
        float rf = __expf(runmax[mf][r] - nm);
        float rs = 0.f;
#pragma unroll
        for (int nf = 0; nf < 8; ++nf) {
          float p = __expf(S[mf][nf][r] - nm);
          S[mf][nf][r] = p;
          rs += p;
        }
        rs += __shfl_xor(rs, 1);
        rs += __shfl_xor(rs, 2);
        rs += __shfl_xor(rs, 4);
        rs += __shfl_xor(rs, 8);
        runsum[mf][r] = runsum[mf][r] * rf + rs;
        runmax[mf][r] = nm;
#pragma unroll
        for (int vn = 0; vn < 4; ++vn) O[mf][vn][r] *= rf;
      }
    }

    // P (C-layout) -> LDS -> A-layout fragments.  Wave-private; DS in-order.
#pragma unroll
    for (int mf = 0; mf < 2; ++mf)
#pragma unroll
      for (int nf = 0; nf < 8; ++nf)
#pragma unroll
        for (int r = 0; r < 4; ++r)
          u.Ps[wv][mf * 16 + lg * 4 + r][nf * 16 + lr] = (bf16)S[mf][nf][r];

#pragma unroll
    for (int ks = 0; ks < 4; ++ks) {
      bf16x8 pf0 = *(const bf16x8*)(&u.Ps[wv][lr][ks * 32 + lg * 8]);
      bf16x8 pf1 = *(const bf16x8*)(&u.Ps[wv][16 + lr][ks * 32 + lg * 8]);
#pragma unroll
      for (int vn = 0; vn < 4; ++vn) {
        bf16x8 vf = *(const bf16x8*)(&VTs[vn * 16 + lr][ks * 32 + lg * 8]);
        O[0][vn] = MFMA16(pf0, vf, O[0][vn]);
        O[1][vn] = MFMA16(pf1, vf, O[1][vn]);
      }
    }
  }

#pragma unroll
  for (int mf = 0; mf < 2; ++mf)
#pragma unroll
    for (int vn = 0; vn < 4; ++vn)
#pragma unroll
      for (int r = 0; r < 4; ++r) {
        int tok = q0 + wv * 32 + mf * 16 + lg * 4 + r;
        int d = vn * 16 + lr;
        float o = O[mf][vn][r] / runsum[mf][r];
        ATT[((size_t)bp * 384 + tok) * 768 + h * 64 + d] = (bf16)o;
      }
}

// ---------------------------------------------------------------------------
// Kernel 3: output projection. 256x256 tile, BK=64, f32 out + bias.
// ---------------------------------------------------------------------------
__global__ __launch_bounds__(512, 2) void proj_kernel(
    const bf16* __restrict__ A, const bf16* __restrict__ W,
    const float* __restrict__ bias, float* __restrict__ out)
{
  __shared__ bf16 As[2][256][64];
  __shared__ bf16 Bs[2][256][64];
  int bid = blockIdx.x;                    // 288 blocks
  int swz = (bid & 7) * 36 + (bid >> 3);   // 288 = 8*36
  const int nt = swz % 3, mt = swz / 3;
  const int m0 = mt * 256, n0 = nt * 256;
  const int tid = threadIdx.x;
  const int lane = tid & 63;
  const int wv = tid >> 6;
  const int wm = wv >> 2, wn = wv & 3;
  const int lr = lane & 15, lg = lane >> 4;

  const bf16* Ap = A + (size_t)m0 * 768;
  const bf16* Wp = W + (size_t)n0 * 768;

  f32x4 acc[8][4] = {};

  GEMM_8PHASE_LOOP(Ap, Wp);

#pragma unroll
  for (int mf = 0; mf < 8; ++mf)
#pragma unroll
    for (int nf = 0; nf < 4; ++nf)
#pragma unroll
      for (int r = 0; r < 4; ++r) {
        int m = m0 + wm * 128 + mf * 16 + lg * 4 + r;
        int n = n0 + wn * 64 + nf * 16 + lr;
        out[(size_t)m * 768 + n] = acc[mf][nf][r] + bias[n];
      }
}

// ---------------------------------------------------------------------------
extern "C" void kernel_launch(void* const* d_in, const int* in_sizes, int n_in,
                              void* d_out, int out_size, void* d_ws, size_t ws_size,
                              hipStream_t stream) {
  (void)in_sizes; (void)n_in; (void)out_size; (void)ws_size;
  const float* xv     = (const float*)d_in[0];
  const float* xi     = (const float*)d_in[1];
  const float* qkv_w  = (const float*)d_in[2];
  const float* proj_w = (const float*)d_in[3];
  const float* proj_b = (const float*)d_in[4];
  float* out = (float*)d_out;

  // bf16 scratch inside d_out (75.5 MB): Xb [24576][768] then Wq [2304][768].
  bf16* Xb = (bf16*)d_out;
  bf16* Wq = Xb + (size_t)18874368;

  // ws: Q | K | V | ATT, each 18874368 bf16 (~36 MB) = 151 MB total.
  const size_t SZ = (size_t)64 * 12 * 384 * 64;
  bf16* Q   = (bf16*)d_ws;
  bf16* K   = Q + SZ;
  bf16* V   = K + SZ;
  bf16* ATT = V + SZ;
  bf16* Wp  = Q;                 // proj_w bf16, reuses Q region after attn

  convert1_kernel<<<2048, 256, 0, stream>>>(xv, xi, qkv_w, Xb);
  qkv_kernel<<<864, 512, 0, stream>>>(Xb, Wq, Q, K, V);
  attn_kernel<<<64 * 12 * 3, 256, 0, stream>>>(Q, K, V, ATT);
  convert2_kernel<<<288, 256, 0, stream>>>(proj_w, Wp);
  proj_kernel<<<288, 512, 0, stream>>>(ATT, Wp, proj_b, out);
}

// Round 7
// 311.240 us; speedup vs baseline: 1.2533x; 1.2533x over previous
//
#include <hip/hip_runtime.h>

typedef __bf16 bf16;
typedef __bf16 bf16x8 __attribute__((ext_vector_type(8)));
typedef float f32x4 __attribute__((ext_vector_type(4)));

#define MFMA16(a,b,c) __builtin_amdgcn_mfma_f32_16x16x32_bf16((a),(b),(c),0,0,0)
#define SBAR() __builtin_amdgcn_s_barrier()
#define SCHED0() __builtin_amdgcn_sched_barrier(0)

// Shapes (fixed): B=32, N=384, C=768, H=12, Dh=64, mt=128, 2B=64 batches.
// Global inputs/outputs FLOAT32; intermediates bf16.
// Xb (x bf16 [24576][768]) + Wq (qkv_w bf16 [2304][768]) live in d_out scratch.
// ws: Q | K | V | ATT (each 36 MB bf16) = 151 MB; Wp reuses Q after attn.
//
// GEMMs: 256x256 tile, BK=64, 8 waves (2Mx4N), per-wave 128x64, dbuf LDS.
// r7 change vs r5: counted-vmcnt pipeline (T4). Per K-tile t:
//   reads(buf c) -> lgkmcnt(0) -> s_barrier -> issue tile t+2 loads into buf c
//   -> MFMA x64 -> vmcnt(8) [= tile t+1's loads done, per-wave count +
//   barrier = collective] -> s_barrier.  Prefetch distance 2 tiles (~1500 cy
//   in flight) instead of r5's 0 (its __syncthreads drained vmcnt to 0 each
//   iteration right after issuing the prefetch).
// 8-slot XOR swizzle (slot ^= row&7) on BOTH store-source and read (T2).

__device__ inline void gload16(const bf16* g, bf16* l) {
  __builtin_amdgcn_global_load_lds(
      (const __attribute__((address_space(1))) void*)g,
      (__attribute__((address_space(3))) void*)l, 16, 0, 0);
}

// Stage a 256x64 bf16 tile (32 KB) from a row-major [*,768] panel: 4 gload16
// per thread. LDS linear dest; global column chunk pre-swizzled
// (chunk = (s&7)^(row&7)) so swizzled reads see linear data.
__device__ inline void stage_tile64(const bf16* __restrict__ gsrc,
                                    bf16* lds_base, int tid, int wv) {
#pragma unroll
  for (int r = 0; r < 4; ++r) {
    int s = r * 512 + tid;                        // 0..2047
    int row = s >> 3;
    int chunk = (s & 7) ^ (row & 7);
    gload16(gsrc + (size_t)row * 768 + chunk * 8,
            lds_base + (size_t)(r * 512 + wv * 64) * 8);
  }
}

// Read a 16B MFMA fragment at (row, ksub, lg) from a swizzled 256x64 tile.
__device__ inline bf16x8 frag64(const bf16* buf, int row, int ks, int lg) {
  int slot = ((ks << 2) | lg) ^ (row & 7);
  return *(const bf16x8*)(buf + (size_t)row * 64 + slot * 8);
}

// Counted-vmcnt K-loop over 12 tiles of BK=64. Needs As/Bs[2][256][64],
// acc[8][4], and wm/wn/lr/lg/tid/wv in scope.
#define GEMM_PIPE_LOOP(APANEL, BPANEL)                                          \
  do {                                                                          \
    stage_tile64((APANEL), &As[0][0][0], tid, wv);                              \
    stage_tile64((BPANEL), &Bs[0][0][0], tid, wv);                              \
    stage_tile64((APANEL) + 64, &As[1][0][0], tid, wv);                         \
    stage_tile64((BPANEL) + 64, &Bs[1][0][0], tid, wv);                         \
    asm volatile("s_waitcnt vmcnt(8)" ::: "memory"); SCHED0();                  \
    SBAR();                                                                     \
    int c = 0;                                                                  \
    for (int t = 0; t < 12; ++t) {                                              \
      const bf16* Ab = &As[c][0][0];                                            \
      const bf16* Bb = &Bs[c][0][0];                                            \
      bf16x8 bfrag[4][2], af0[4][2];                                            \
      _Pragma("unroll")                                                         \
      for (int nf = 0; nf < 4; ++nf)                                            \
        _Pragma("unroll")                                                       \
        for (int ks = 0; ks < 2; ++ks)                                          \
          bfrag[nf][ks] = frag64(Bb, wn * 64 + nf * 16 + lr, ks, lg);           \
      _Pragma("unroll")                                                         \
      for (int i = 0; i < 4; ++i)                                               \
        _Pragma("unroll")                                                       \
        for (int ks = 0; ks < 2; ++ks)                                          \
          af0[i][ks] = frag64(Ab, wm * 128 + i * 16 + lr, ks, lg);              \
      __builtin_amdgcn_s_setprio(1);                                            \
      _Pragma("unroll")                                                         \
      for (int i = 0; i < 4; ++i)                                               \
        _Pragma("unroll")                                                       \
        for (int nf = 0; nf < 4; ++nf)                                          \
          _Pragma("unroll")                                                     \
          for (int ks = 0; ks < 2; ++ks)                                        \
            acc[i][nf] = MFMA16(af0[i][ks], bfrag[nf][ks], acc[i][nf]);         \
      __builtin_amdgcn_s_setprio(0);                                            \
      bf16x8 af1[4][2];                                                         \
      _Pragma("unroll")                                                         \
      for (int i = 0; i < 4; ++i)                                               \
        _Pragma("unroll")                                                       \
        for (int ks = 0; ks < 2; ++ks)                                          \
          af1[i][ks] = frag64(Ab, wm * 128 + (4 + i) * 16 + lr, ks, lg);        \
      asm volatile("s_waitcnt lgkmcnt(0)" ::: "memory"); SCHED0();              \
      SBAR();   /* all waves done reading buf[c] -> safe to refill */           \
      if (t + 2 < 12) {                                                         \
        stage_tile64((APANEL) + (t + 2) * 64, &As[c][0][0], tid, wv);           \
        stage_tile64((BPANEL) + (t + 2) * 64, &Bs[c][0][0], tid, wv);           \
      }                                                                         \
      __builtin_amdgcn_s_setprio(1);                                            \
      _Pragma("unroll")                                                         \
      for (int i = 0; i < 4; ++i)                                               \
        _Pragma("unroll")                                                       \
        for (int nf = 0; nf < 4; ++nf)                                          \
          _Pragma("unroll")                                                     \
          for (int ks = 0; ks < 2; ++ks)                                        \
            acc[4 + i][nf] = MFMA16(af1[i][ks], bfrag[nf][ks], acc[4 + i][nf]); \
      __builtin_amdgcn_s_setprio(0);                                            \
      if (t < 10) { asm volatile("s_waitcnt vmcnt(8)" ::: "memory"); }          \
      else        { asm volatile("s_waitcnt vmcnt(0)" ::: "memory"); }          \
      SCHED0();                                                                 \
      SBAR();   /* buf[c^1] (tile t+1) now globally ready */                    \
      c ^= 1;                                                                   \
    }                                                                           \
  } while (0)

// ---------------------------------------------------------------------------
// convert1: pack xv | xi | qkv_w (f32) -> bf16 into d_out scratch.
// ---------------------------------------------------------------------------
__global__ __launch_bounds__(256) void convert1_kernel(
    const float* __restrict__ xv, const float* __restrict__ xi,
    const float* __restrict__ w, bf16* __restrict__ dst)
{
  const size_t NV = 9437184;     // 12288*768
  const size_t NX = 18874368;    // 2*NV
  const size_t NT = 20643840;    // NX + 1769472 (qkv_w)
  for (size_t i = (size_t)blockIdx.x * 256 + threadIdx.x; i * 8 < NT;
       i += (size_t)gridDim.x * 256) {
    size_t e = i * 8;
    const float* src;
    if (e < NV)      src = xv + e;
    else if (e < NX) src = xi + (e - NV);
    else             src = w + (e - NX);
    f32x4 a = *(const f32x4*)src;
    f32x4 b = *(const f32x4*)(src + 4);
    bf16x8 r;
    r[0] = (bf16)a[0]; r[1] = (bf16)a[1]; r[2] = (bf16)a[2]; r[3] = (bf16)a[3];
    r[4] = (bf16)b[0]; r[5] = (bf16)b[1]; r[6] = (bf16)b[2]; r[7] = (bf16)b[3];
    *(bf16x8*)(dst + e) = r;
  }
}

// convert2: proj_w (f32, 589824) -> bf16 (into dead Q region).
__global__ __launch_bounds__(256) void convert2_kernel(
    const float* __restrict__ w, bf16* __restrict__ dst)
{
  size_t i = (size_t)blockIdx.x * 256 + threadIdx.x;
  size_t e = i * 8;
  if (e >= 589824) return;
  f32x4 a = *(const f32x4*)(w + e);
  f32x4 b = *(const f32x4*)(w + e + 4);
  bf16x8 r;
  r[0] = (bf16)a[0]; r[1] = (bf16)a[1]; r[2] = (bf16)a[2]; r[3] = (bf16)a[3];
  r[4] = (bf16)b[0]; r[5] = (bf16)b[1]; r[6] = (bf16)b[2]; r[7] = (bf16)b[3];
  *(bf16x8*)(dst + e) = r;
}

// ---------------------------------------------------------------------------
// Kernel 1: QKV projection. 256x256 tile, BK=64, scatter epilogue to Q/K/V.
// ---------------------------------------------------------------------------
__global__ __launch_bounds__(512, 2) void qkv_kernel(
    const bf16* __restrict__ X, const bf16* __restrict__ W,
    bf16* __restrict__ Qo, bf16* __restrict__ Ko, bf16* __restrict__ Vo)
{
  __shared__ bf16 As[2][256][64];
  __shared__ bf16 Bs[2][256][64];
  int bid = blockIdx.x;                    // 864 blocks
  int swz = (bid & 7) * 108 + (bid >> 3);  // XCD-contiguous, bijective (864=8*108)
  const int nt = swz % 9, mt = swz / 9;
  const int m0 = mt * 256, n0 = nt * 256;
  const int tid = threadIdx.x;
  const int lane = tid & 63;
  const int wv = tid >> 6;                 // 0..7
  const int wm = wv >> 2, wn = wv & 3;     // 2x4 wave grid; wave out 128x64
  const int lr = lane & 15, lg = lane >> 4;

  const bf16* Xp = X + (size_t)m0 * 768;
  const bf16* Wp = W + (size_t)n0 * 768;

  f32x4 acc[8][4] = {};

  GEMM_PIPE_LOOP(Xp, Wp);

#pragma unroll
  for (int mf = 0; mf < 8; ++mf)
#pragma unroll
    for (int nf = 0; nf < 4; ++nf)
#pragma unroll
      for (int r = 0; r < 4; ++r) {
        int m = m0 + wm * 128 + mf * 16 + lg * 4 + r;
        int n = n0 + wn * 64 + nf * 16 + lr;
        int bp = m / 384, tok = m - bp * 384;
        int comp = (n >= 1536) ? 2 : (n >= 768) ? 1 : 0;
        int rem = n - comp * 768;
        int hh = rem >> 6, d = rem & 63;
        size_t addr = (((size_t)bp * 12 + hh) * 384 + tok) * 64 + d;
        float val = acc[mf][nf][r];
        if (comp == 0)      Qo[addr] = (bf16)(val * 0.125f);   // fold 1/sqrt(Dh)
        else if (comp == 1) Ko[addr] = (bf16)val;
        else                Vo[addr] = (bf16)val;
      }
}

// ---------------------------------------------------------------------------
// Kernel 2: attention (unchanged, verified). grid = 64*12*3.
// ---------------------------------------------------------------------------
__global__ __launch_bounds__(256) void attn_kernel(
    const bf16* __restrict__ Q, const bf16* __restrict__ K, const bf16* __restrict__ V,
    bf16* __restrict__ ATT)
{
  __shared__ union {
    bf16 Qs[128][72];
    bf16 Ps[4][32][136];     // per-wave P tile (Qs dead after qf reg-cache)
  } u;
  __shared__ bf16 Ks[128][72];
  __shared__ bf16 VTs[64][136];     // transposed V: [d][token]

  const int bid = blockIdx.x;
  const int qb = bid % 3;
  const int h  = (bid / 3) % 12;
  const int bp = bid / 36;           // b' in [0,64)
  const int tid = threadIdx.x;
  const int lane = tid & 63;
  const int wv = tid >> 6;
  const int lr = lane & 15, lg = lane >> 4;

  const size_t bh384 = ((size_t)bp * 12 + h) * 384;
  const int q0 = qb * 128;

  for (int v = tid; v < 1024; v += 256) {
    int row = v >> 3, cg = (v & 7) * 8;
    *(bf16x8*)(&u.Qs[row][cg]) = *(const bf16x8*)(Q + (bh384 + q0 + row) * 64 + cg);
  }
  __syncthreads();

  bf16x8 qf[2][2];
#pragma unroll
  for (int mf = 0; mf < 2; ++mf)
#pragma unroll
    for (int ks = 0; ks < 2; ++ks)
      qf[mf][ks] = *(const bf16x8*)(&u.Qs[wv * 32 + mf * 16 + lr][ks * 32 + lg * 8]);

  f32x4 O[2][4] = {};
  float runmax[2][4], runsum[2][4];
#pragma unroll
  for (int mf = 0; mf < 2; ++mf)
#pragma unroll
    for (int r = 0; r < 4; ++r) { runmax[mf][r] = -1e30f; runsum[mf][r] = 0.f; }

  const int nchunks = (qb == 0) ? 1 : 4;
  for (int c = 0; c < nchunks; ++c) {
    int src_b, t0;
    if (qb == 0)      { src_b = bp;            t0 = 0; }
    else if (c == 0)  { src_b = bp & 31;       t0 = 0; }          // mt of V batch
    else if (c == 1)  { src_b = (bp & 31)+32;  t0 = 0; }          // mt of I batch
    else              { src_b = bp;            t0 = (c - 1) * 128; } // own s tokens
    const size_t kb = (((size_t)src_b * 12 + h) * 384 + t0) * 64;

    __syncthreads();   // previous chunk fully consumed before restaging
    for (int v = tid; v < 1024; v += 256) {
      int row = v >> 3, cg = (v & 7) * 8;
      *(bf16x8*)(&Ks[row][cg]) = *(const bf16x8*)(K + kb + row * 64 + cg);
      bf16x8 vvld = *(const bf16x8*)(V + kb + row * 64 + cg);
#pragma unroll
      for (int j = 0; j < 8; ++j) VTs[cg + j][row] = vvld[j];
    }
    __syncthreads();

    // S = Q * Kc^T   (scale already folded into Q)
    f32x4 S[2][8] = {};
#pragma unroll
    for (int nf = 0; nf < 8; ++nf) {
#pragma unroll
      for (int ks = 0; ks < 2; ++ks) {
        bf16x8 kf = *(const bf16x8*)(&Ks[nf * 16 + lr][ks * 32 + lg * 8]);
        S[0][nf] = MFMA16(qf[0][ks], kf, S[0][nf]);
        S[1][nf] = MFMA16(qf[1][ks], kf, S[1][nf]);
      }
    }

    // online softmax (row = lg*4 + r within 16-row fragment; 16-lane reduce)
#pragma unroll
    for (int mf = 0; mf < 2; ++mf) {
#pragma unroll
      for (int r = 0; r < 4; ++r) {
        float mx = S[mf][0][r];
#pragma unroll
        for (int nf = 1; nf < 8; ++nf) mx = fmaxf(mx, S[mf][nf][r]);
        mx = fmaxf(mx, __shfl_xor(mx, 1));
        mx = fmaxf(mx, __shfl_xor(mx, 2));
        mx = fmaxf(mx, __shfl_xor(mx, 4));
        mx = fmaxf(mx, __shfl_xor(mx, 8));
        float nm = fmaxf(runmax[mf][r], mx);
        float rf = __expf(runmax[mf][r] - nm);
        float rs = 0.f;
#pragma unroll
        for (int nf = 0; nf < 8; ++nf) {
          float p = __expf(S[mf][nf][r] - nm);
          S[mf][nf][r] = p;
          rs += p;
        }
        rs += __shfl_xor(rs, 1);
        rs += __shfl_xor(rs, 2);
        rs += __shfl_xor(rs, 4);
        rs += __shfl_xor(rs, 8);
        runsum[mf][r] = runsum[mf][r] * rf + rs;
        runmax[mf][r] = nm;
#pragma unroll
        for (int vn = 0; vn < 4; ++vn) O[mf][vn][r] *= rf;
      }
    }

    // P (C-layout) -> LDS -> A-layout fragments.  Wave-private; DS in-order.
#pragma unroll
    for (int mf = 0; mf < 2; ++mf)
#pragma unroll
      for (int nf = 0; nf < 8; ++nf)
#pragma unroll
        for (int r = 0; r < 4; ++r)
          u.Ps[wv][mf * 16 + lg * 4 + r][nf * 16 + lr] = (bf16)S[mf][nf][r];

#pragma unroll
    for (int ks = 0; ks < 4; ++ks) {
      bf16x8 pf0 = *(const bf16x8*)(&u.Ps[wv][lr][ks * 32 + lg * 8]);
      bf16x8 pf1 = *(const bf16x8*)(&u.Ps[wv][16 + lr][ks * 32 + lg * 8]);
#pragma unroll
      for (int vn = 0; vn < 4; ++vn) {
        bf16x8 vf = *(const bf16x8*)(&VTs[vn * 16 + lr][ks * 32 + lg * 8]);
        O[0][vn] = MFMA16(pf0, vf, O[0][vn]);
        O[1][vn] = MFMA16(pf1, vf, O[1][vn]);
      }
    }
  }

#pragma unroll
  for (int mf = 0; mf < 2; ++mf)
#pragma unroll
    for (int vn = 0; vn < 4; ++vn)
#pragma unroll
      for (int r = 0; r < 4; ++r) {
        int tok = q0 + wv * 32 + mf * 16 + lg * 4 + r;
        int d = vn * 16 + lr;
        float o = O[mf][vn][r] / runsum[mf][r];
        ATT[((size_t)bp * 384 + tok) * 768 + h * 64 + d] = (bf16)o;
      }
}

// ---------------------------------------------------------------------------
// Kernel 3: output projection. 256x256 tile, BK=64, f32 out + bias.
// ---------------------------------------------------------------------------
__global__ __launch_bounds__(512, 2) void proj_kernel(
    const bf16* __restrict__ A, const bf16* __restrict__ W,
    const float* __restrict__ bias, float* __restrict__ out)
{
  __shared__ bf16 As[2][256][64];
  __shared__ bf16 Bs[2][256][64];
  int bid = blockIdx.x;                    // 288 blocks
  int swz = (bid & 7) * 36 + (bid >> 3);   // 288 = 8*36
  const int nt = swz % 3, mt = swz / 3;
  const int m0 = mt * 256, n0 = nt * 256;
  const int tid = threadIdx.x;
  const int lane = tid & 63;
  const int wv = tid >> 6;
  const int wm = wv >> 2, wn = wv & 3;
  const int lr = lane & 15, lg = lane >> 4;

  const bf16* Ap = A + (size_t)m0 * 768;
  const bf16* Wpp = W + (size_t)n0 * 768;

  f32x4 acc[8][4] = {};

  GEMM_PIPE_LOOP(Ap, Wpp);

#pragma unroll
  for (int mf = 0; mf < 8; ++mf)
#pragma unroll
    for (int nf = 0; nf < 4; ++nf)
#pragma unroll
      for (int r = 0; r < 4; ++r) {
        int m = m0 + wm * 128 + mf * 16 + lg * 4 + r;
        int n = n0 + wn * 64 + nf * 16 + lr;
        out[(size_t)m * 768 + n] = acc[mf][nf][r] + bias[n];
      }
}

// ---------------------------------------------------------------------------
extern "C" void kernel_launch(void* const* d_in, const int* in_sizes, int n_in,
                              void* d_out, int out_size, void* d_ws, size_t ws_size,
                              hipStream_t stream) {
  (void)in_sizes; (void)n_in; (void)out_size; (void)ws_size;
  const float* xv     = (const float*)d_in[0];
  const float* xi     = (const float*)d_in[1];
  const float* qkv_w  = (const float*)d_in[2];
  const float* proj_w = (const float*)d_in[3];
  const float* proj_b = (const float*)d_in[4];
  float* out = (float*)d_out;

  // bf16 scratch inside d_out (75.5 MB): Xb [24576][768] then Wq [2304][768].
  bf16* Xb = (bf16*)d_out;
  bf16* Wq = Xb + (size_t)18874368;

  // ws: Q | K | V | ATT, each 18874368 bf16 (~36 MB) = 151 MB total.
  const size_t SZ = (size_t)64 * 12 * 384 * 64;
  bf16* Q   = (bf16*)d_ws;
  bf16* K   = Q + SZ;
  bf16* V   = K + SZ;
  bf16* ATT = V + SZ;
  bf16* Wp  = Q;                 // proj_w bf16, reuses Q region after attn

  convert1_kernel<<<2048, 256, 0, stream>>>(xv, xi, qkv_w, Xb);
  qkv_kernel<<<864, 512, 0, stream>>>(Xb, Wq, Q, K, V);
  attn_kernel<<<64 * 12 * 3, 256, 0, stream>>>(Q, K, V, ATT);
  convert2_kernel<<<288, 256, 0, stream>>>(proj_w, Wp);
  proj_kernel<<<288, 512, 0, stream>>>(ATT, Wp, proj_b, out);
}

// Round 8
// 296.653 us; speedup vs baseline: 1.3149x; 1.0492x over previous
//
#include <hip/hip_runtime.h>

typedef __bf16 bf16;
typedef __bf16 bf16x4 __attribute__((ext_vector_type(4)));
typedef __bf16 bf16x8 __attribute__((ext_vector_type(8)));
typedef float f32x4 __attribute__((ext_vector_type(4)));

#define MFMA16(a,b,c) __builtin_amdgcn_mfma_f32_16x16x32_bf16((a),(b),(c),0,0,0)
#define SBAR() __builtin_amdgcn_s_barrier()
#define SCHED0() __builtin_amdgcn_sched_barrier(0)

// Shapes (fixed): B=32, N=384, C=768, H=12, Dh=64, mt=128, 2B=64 batches.
// Global inputs/outputs FLOAT32; intermediates bf16.
// Xb (x bf16 [24576][768]) + Wq (qkv_w bf16 [2304][768]) live in d_out scratch.
// ws: Q | K | VT | ATT (each 36 MB bf16) = 151 MB; Wp reuses Q after attn.
// V is stored TRANSPOSED (VT[b'][h][d][tok]) by the qkv epilogue so attn's
// PV staging is fully vectorized (was 32 scalar ds_writes/thread/chunk).
//
// GEMMs (qkv + proj): 128x128 tile, BK=64, 4 waves (2x2), 64 KB LDS ->
// 2 blocks/CU co-resident (r7's 256x256 was register+LDS capped at 1).
// Counted-vmcnt 2-tile-ahead pipeline; both-sides XOR swizzle (T2).

__device__ inline void gload16(const bf16* g, bf16* l) {
  __builtin_amdgcn_global_load_lds(
      (const __attribute__((address_space(1))) void*)g,
      (__attribute__((address_space(3))) void*)l, 16, 0, 0);
}

// Stage a 128x64 bf16 tile (16 KB) from a row-major [*,768] panel; 256 thr,
// 4 gload16 each. LDS linear dest; source column chunk pre-swizzled
// (chunk = (s&7)^(row&7)) so swizzled reads see the right data.
__device__ inline void stage128(const bf16* __restrict__ gsrc,
                                bf16* lds_base, int tid, int wv) {
#pragma unroll
  for (int r = 0; r < 4; ++r) {
    int s = r * 256 + tid;                        // 0..1023
    int row = s >> 3;
    int chunk = (s & 7) ^ (row & 7);
    gload16(gsrc + (size_t)row * 768 + chunk * 8,
            lds_base + (size_t)(r * 256 + wv * 64) * 8);
  }
}

// Read a 16B MFMA fragment at (row, ksub, lg) from a swizzled *x64 tile.
__device__ inline bf16x8 frag64(const bf16* buf, int row, int ks, int lg) {
  int slot = ((ks << 2) | lg) ^ (row & 7);
  return *(const bf16x8*)(buf + (size_t)row * 64 + slot * 8);
}

// Counted-vmcnt K-loop over NTILES tiles of BK=64. Needs As/Bs[2][128][64],
// acc[4][4], wr/wc/lr/lg/tid/wv in scope.
#define GEMM128_LOOP(APANEL, BPANEL, NTILES)                                    \
  do {                                                                          \
    stage128((APANEL), &As[0][0][0], tid, wv);                                  \
    stage128((BPANEL), &Bs[0][0][0], tid, wv);                                  \
    stage128((APANEL) + 64, &As[1][0][0], tid, wv);                             \
    stage128((BPANEL) + 64, &Bs[1][0][0], tid, wv);                             \
    asm volatile("s_waitcnt vmcnt(8)" ::: "memory"); SCHED0();                  \
    SBAR();                                                                     \
    int c = 0;                                                                  \
    for (int t = 0; t < (NTILES); ++t) {                                        \
      const bf16* Ab = &As[c][0][0];                                            \
      const bf16* Bb = &Bs[c][0][0];                                            \
      bf16x8 af[4][2], bfr[4][2];                                               \
      _Pragma("unroll")                                                         \
      for (int nf = 0; nf < 4; ++nf)                                            \
        _Pragma("unroll")                                                       \
        for (int ks = 0; ks < 2; ++ks)                                          \
          bfr[nf][ks] = frag64(Bb, wc + nf * 16 + lr, ks, lg);                  \
      _Pragma("unroll")                                                         \
      for (int mf = 0; mf < 4; ++mf)                                            \
        _Pragma("unroll")                                                       \
        for (int ks = 0; ks < 2; ++ks)                                          \
          af[mf][ks] = frag64(Ab, wr + mf * 16 + lr, ks, lg);                   \
      asm volatile("s_waitcnt lgkmcnt(0)" ::: "memory"); SCHED0();              \
      SBAR();   /* all waves done reading buf[c] -> safe to refill */           \
      if (t + 2 < (NTILES)) {                                                   \
        stage128((APANEL) + (t + 2) * 64, &As[c][0][0], tid, wv);               \
        stage128((BPANEL) + (t + 2) * 64, &Bs[c][0][0], tid, wv);               \
      }                                                                         \
      __builtin_amdgcn_s_setprio(1);                                            \
      _Pragma("unroll")                                                         \
      for (int mf = 0; mf < 4; ++mf)                                            \
        _Pragma("unroll")                                                       \
        for (int nf = 0; nf < 4; ++nf)                                          \
          _Pragma("unroll")                                                     \
          for (int ks = 0; ks < 2; ++ks)                                        \
            acc[mf][nf] = MFMA16(af[mf][ks], bfr[nf][ks], acc[mf][nf]);         \
      __builtin_amdgcn_s_setprio(0);                                            \
      if (t + 2 < (NTILES)) { asm volatile("s_waitcnt vmcnt(8)" ::: "memory"); }\
      else                  { asm volatile("s_waitcnt vmcnt(0)" ::: "memory"); }\
      SCHED0();                                                                 \
      SBAR();   /* buf[c^1] (tile t+1) now globally ready */                    \
      c ^= 1;                                                                   \
    }                                                                           \
  } while (0)

// ---------------------------------------------------------------------------
// convert1: pack xv | xi | qkv_w (f32) -> bf16 into d_out scratch.
// ---------------------------------------------------------------------------
__global__ __launch_bounds__(256) void convert1_kernel(
    const float* __restrict__ xv, const float* __restrict__ xi,
    const float* __restrict__ w, bf16* __restrict__ dst)
{
  const size_t NV = 9437184;     // 12288*768
  const size_t NX = 18874368;    // 2*NV
  const size_t NT = 20643840;    // NX + 1769472 (qkv_w)
  for (size_t i = (size_t)blockIdx.x * 256 + threadIdx.x; i * 8 < NT;
       i += (size_t)gridDim.x * 256) {
    size_t e = i * 8;
    const float* src;
    if (e < NV)      src = xv + e;
    else if (e < NX) src = xi + (e - NV);
    else             src = w + (e - NX);
    f32x4 a = *(const f32x4*)src;
    f32x4 b = *(const f32x4*)(src + 4);
    bf16x8 r;
    r[0] = (bf16)a[0]; r[1] = (bf16)a[1]; r[2] = (bf16)a[2]; r[3] = (bf16)a[3];
    r[4] = (bf16)b[0]; r[5] = (bf16)b[1]; r[6] = (bf16)b[2]; r[7] = (bf16)b[3];
    *(bf16x8*)(dst + e) = r;
  }
}

// convert2: proj_w (f32, 589824) -> bf16 (into dead Q region).
__global__ __launch_bounds__(256) void convert2_kernel(
    const float* __restrict__ w, bf16* __restrict__ dst)
{
  size_t i = (size_t)blockIdx.x * 256 + threadIdx.x;
  size_t e = i * 8;
  if (e >= 589824) return;
  f32x4 a = *(const f32x4*)(w + e);
  f32x4 b = *(const f32x4*)(w + e + 4);
  bf16x8 r;
  r[0] = (bf16)a[0]; r[1] = (bf16)a[1]; r[2] = (bf16)a[2]; r[3] = (bf16)a[3];
  r[4] = (bf16)b[0]; r[5] = (bf16)b[1]; r[6] = (bf16)b[2]; r[7] = (bf16)b[3];
  *(bf16x8*)(dst + e) = r;
}

// ---------------------------------------------------------------------------
// Kernel 1: QKV projection. 128x128 tile, BK=64. Scatter epilogue: Q scaled,
// K row-major, V transposed (VT[b'][h][d][tok], 4 tok packed per 8B store).
// ---------------------------------------------------------------------------
__global__ __launch_bounds__(256, 2) void qkv_kernel(
    const bf16* __restrict__ X, const bf16* __restrict__ W,
    bf16* __restrict__ Qo, bf16* __restrict__ Ko, bf16* __restrict__ VTo)
{
  __shared__ bf16 As[2][128][64];
  __shared__ bf16 Bs[2][128][64];
  int bid = blockIdx.x;                    // 3456 blocks
  int swz = (bid & 7) * 432 + (bid >> 3);  // XCD-contiguous, bijective
  const int nt = swz % 18, mt = swz / 18;
  const int m0 = mt * 128, n0 = nt * 128;
  const int tid = threadIdx.x;
  const int lane = tid & 63;
  const int wv = tid >> 6;                 // 0..3
  const int wr = (wv >> 1) * 64, wc = (wv & 1) * 64;
  const int lr = lane & 15, lg = lane >> 4;

  const bf16* Xp = X + (size_t)m0 * 768;
  const bf16* Wp = W + (size_t)n0 * 768;

  f32x4 acc[4][4] = {};

  GEMM128_LOOP(Xp, Wp, 12);

#pragma unroll
  for (int mf = 0; mf < 4; ++mf)
#pragma unroll
    for (int nf = 0; nf < 4; ++nf) {
      int m = m0 + wr + mf * 16 + lg * 4;       // 4-aligned token base
      int n = n0 + wc + nf * 16 + lr;
      int bp = m / 384, tok = m - bp * 384;
      int comp = (n >= 1536) ? 2 : (n >= 768) ? 1 : 0;
      int rem = n - comp * 768;
      int hh = rem >> 6, d = rem & 63;
      if (comp == 2) {
        bf16x4 pk;
        pk[0] = (bf16)acc[mf][nf][0]; pk[1] = (bf16)acc[mf][nf][1];
        pk[2] = (bf16)acc[mf][nf][2]; pk[3] = (bf16)acc[mf][nf][3];
        *(bf16x4*)(VTo + (((size_t)bp * 12 + hh) * 64 + d) * 384 + tok) = pk;
      } else {
#pragma unroll
        for (int r = 0; r < 4; ++r) {
          size_t addr = (((size_t)bp * 12 + hh) * 384 + tok + r) * 64 + d;
          float val = acc[mf][nf][r];
          if (comp == 0) Qo[addr] = (bf16)(val * 0.125f);  // fold 1/sqrt(Dh)
          else           Ko[addr] = (bf16)val;
        }
      }
    }
}

// ---------------------------------------------------------------------------
// Kernel 2: attention. grid = 64*12*3. V comes in pre-transposed (VT).
// ---------------------------------------------------------------------------
__global__ __launch_bounds__(256) void attn_kernel(
    const bf16* __restrict__ Q, const bf16* __restrict__ K, const bf16* __restrict__ VT,
    bf16* __restrict__ ATT)
{
  __shared__ union {
    bf16 Qs[128][72];
    bf16 Ps[4][32][136];     // per-wave P tile (Qs dead after qf reg-cache)
  } u;
  __shared__ bf16 Ks[128][72];
  __shared__ bf16 VTs[64][136];     // transposed V: [d][token]

  const int bid = blockIdx.x;
  const int qb = bid % 3;
  const int h  = (bid / 3) % 12;
  const int bp = bid / 36;           // b' in [0,64)
  const int tid = threadIdx.x;
  const int lane = tid & 63;
  const int wv = tid >> 6;
  const int lr = lane & 15, lg = lane >> 4;

  const size_t bh384 = ((size_t)bp * 12 + h) * 384;
  const int q0 = qb * 128;

  for (int v = tid; v < 1024; v += 256) {
    int row = v >> 3, cg = (v & 7) * 8;
    *(bf16x8*)(&u.Qs[row][cg]) = *(const bf16x8*)(Q + (bh384 + q0 + row) * 64 + cg);
  }
  __syncthreads();

  bf16x8 qf[2][2];
#pragma unroll
  for (int mf = 0; mf < 2; ++mf)
#pragma unroll
    for (int ks = 0; ks < 2; ++ks)
      qf[mf][ks] = *(const bf16x8*)(&u.Qs[wv * 32 + mf * 16 + lr][ks * 32 + lg * 8]);

  f32x4 O[2][4] = {};
  float runmax[2][4], runsum[2][4];
#pragma unroll
  for (int mf = 0; mf < 2; ++mf)
#pragma unroll
    for (int r = 0; r < 4; ++r) { runmax[mf][r] = -1e30f; runsum[mf][r] = 0.f; }

  const int nchunks = (qb == 0) ? 1 : 4;
  for (int c = 0; c < nchunks; ++c) {
    int src_b, t0;
    if (qb == 0)      { src_b = bp;            t0 = 0; }          // own mt
    else if (c == 0)  { src_b = bp & 31;       t0 = 0; }          // mt of V batch
    else if (c == 1)  { src_b = (bp & 31)+32;  t0 = 0; }          // mt of I batch
    else              { src_b = bp;            t0 = (c - 1) * 128; } // own s tokens
    const size_t kb  = (((size_t)src_b * 12 + h) * 384 + t0) * 64;
    const size_t vtb = ((size_t)src_b * 12 + h) * 64 * 384 + t0;

    __syncthreads();   // previous chunk fully consumed before restaging
    for (int v = tid; v < 1024; v += 256) {
      int row = v >> 3, cg = (v & 7) * 8;
      *(bf16x8*)(&Ks[row][cg]) = *(const bf16x8*)(K + kb + row * 64 + cg);
    }
    for (int v = tid; v < 1024; v += 256) {
      int d = v >> 4, p = (v & 15) * 8;
      *(bf16x8*)(&VTs[d][p]) = *(const bf16x8*)(VT + vtb + (size_t)d * 384 + p);
    }
    __syncthreads();

    // S = Q * Kc^T   (scale already folded into Q)
    f32x4 S[2][8] = {};
#pragma unroll
    for (int nf = 0; nf < 8; ++nf) {
#pragma unroll
      for (int ks = 0; ks < 2; ++ks) {
        bf16x8 kf = *(const bf16x8*)(&Ks[nf * 16 + lr][ks * 32 + lg * 8]);
        S[0][nf] = MFMA16(qf[0][ks], kf, S[0][nf]);
        S[1][nf] = MFMA16(qf[1][ks], kf, S[1][nf]);
      }
    }

    // online softmax (row = lg*4 + r within 16-row fragment; 16-lane reduce)
#pragma unroll
    for (int mf = 0; mf < 2; ++mf) {
#pragma unroll
      for (int r = 0; r < 4; ++r) {
        float mx = S[mf][0][r];
#pragma unroll
        for (int nf = 1; nf < 8; ++nf) mx = fmaxf(mx, S[mf][nf][r]);
        mx = fmaxf(mx, __shfl_xor(mx, 1));
        mx = fmaxf(mx, __shfl_xor(mx, 2));
        mx = fmaxf(mx, __shfl_xor(mx, 4));
        mx = fmaxf(mx, __shfl_xor(mx, 8));
        float nm = fmaxf(runmax[mf][r], mx);
        float rf = __expf(runmax[mf][r] - nm);
        float rs = 0.f;
#pragma unroll
        for (int nf = 0; nf < 8; ++nf) {
          float p = __expf(S[mf][nf][r] - nm);
          S[mf][nf][r] = p;
          rs += p;
        }
        rs += __shfl_xor(rs, 1);
        rs += __shfl_xor(rs, 2);
        rs += __shfl_xor(rs, 4);
        rs += __shfl_xor(rs, 8);
        runsum[mf][r] = runsum[mf][r] * rf + rs;
        runmax[mf][r] = nm;
#pragma unroll
        for (int vn = 0; vn < 4; ++vn) O[mf][vn][r] *= rf;
      }
    }

    // P (C-layout) -> LDS -> A-layout fragments.  Wave-private; DS in-order.
#pragma unroll
    for (int mf = 0; mf < 2; ++mf)
#pragma unroll
      for (int nf = 0; nf < 8; ++nf)
#pragma unroll
        for (int r = 0; r < 4; ++r)
          u.Ps[wv][mf * 16 + lg * 4 + r][nf * 16 + lr] = (bf16)S[mf][nf][r];

#pragma unroll
    for (int ks = 0; ks < 4; ++ks) {
      bf16x8 pf0 = *(const bf16x8*)(&u.Ps[wv][lr][ks * 32 + lg * 8]);
      bf16x8 pf1 = *(const bf16x8*)(&u.Ps[wv][16 + lr][ks * 32 + lg * 8]);
#pragma unroll
      for (int vn = 0; vn < 4; ++vn) {
        bf16x8 vf = *(const bf16x8*)(&VTs[vn * 16 + lr][ks * 32 + lg * 8]);
        O[0][vn] = MFMA16(pf0, vf, O[0][vn]);
        O[1][vn] = MFMA16(pf1, vf, O[1][vn]);
      }
    }
  }

#pragma unroll
  for (int mf = 0; mf < 2; ++mf)
#pragma unroll
    for (int vn = 0; vn < 4; ++vn)
#pragma unroll
      for (int r = 0; r < 4; ++r) {
        int tok = q0 + wv * 32 + mf * 16 + lg * 4 + r;
        int d = vn * 16 + lr;
        float o = O[mf][vn][r] / runsum[mf][r];
        ATT[((size_t)bp * 384 + tok) * 768 + h * 64 + d] = (bf16)o;
      }
}

// ---------------------------------------------------------------------------
// Kernel 3: output projection. 128x128 tile, BK=64, f32 out + bias.
// ---------------------------------------------------------------------------
__global__ __launch_bounds__(256, 2) void proj_kernel(
    const bf16* __restrict__ A, const bf16* __restrict__ W,
    const float* __restrict__ bias, float* __restrict__ out)
{
  __shared__ bf16 As[2][128][64];
  __shared__ bf16 Bs[2][128][64];
  int bid = blockIdx.x;                    // 1152 blocks
  int swz = (bid & 7) * 144 + (bid >> 3);  // 1152 = 8*144
  const int nt = swz % 6, mt = swz / 6;
  const int m0 = mt * 128, n0 = nt * 128;
  const int tid = threadIdx.x;
  const int lane = tid & 63;
  const int wv = tid >> 6;
  const int wr = (wv >> 1) * 64, wc = (wv & 1) * 64;
  const int lr = lane & 15, lg = lane >> 4;

  const bf16* Ap = A + (size_t)m0 * 768;
  const bf16* Wpp = W + (size_t)n0 * 768;

  f32x4 acc[4][4] = {};

  GEMM128_LOOP(Ap, Wpp, 12);

#pragma unroll
  for (int mf = 0; mf < 4; ++mf)
#pragma unroll
    for (int nf = 0; nf < 4; ++nf)
#pragma unroll
      for (int r = 0; r < 4; ++r) {
        int m = m0 + wr + mf * 16 + lg * 4 + r;
        int n = n0 + wc + nf * 16 + lr;
        out[(size_t)m * 768 + n] = acc[mf][nf][r] + bias[n];
      }
}

// ---------------------------------------------------------------------------
extern "C" void kernel_launch(void* const* d_in, const int* in_sizes, int n_in,
                              void* d_out, int out_size, void* d_ws, size_t ws_size,
                              hipStream_t stream) {
  (void)in_sizes; (void)n_in; (void)out_size; (void)ws_size;
  const float* xv     = (const float*)d_in[0];
  const float* xi     = (const float*)d_in[1];
  const float* qkv_w  = (const float*)d_in[2];
  const float* proj_w = (const float*)d_in[3];
  const float* proj_b = (const float*)d_in[4];
  float* out = (float*)d_out;

  // bf16 scratch inside d_out (75.5 MB): Xb [24576][768] then Wq [2304][768].
  bf16* Xb = (bf16*)d_out;
  bf16* Wq = Xb + (size_t)18874368;

  // ws: Q | K | VT | ATT, each 18874368 bf16 (~36 MB) = 151 MB total.
  const size_t SZ = (size_t)64 * 12 * 384 * 64;
  bf16* Q   = (bf16*)d_ws;
  bf16* K   = Q + SZ;
  bf16* VT  = K + SZ;
  bf16* ATT = VT + SZ;
  bf16* Wp  = Q;                 // proj_w bf16, reuses Q region after attn

  convert1_kernel<<<2048, 256, 0, stream>>>(xv, xi, qkv_w, Xb);
  qkv_kernel<<<3456, 256, 0, stream>>>(Xb, Wq, Q, K, VT);
  attn_kernel<<<64 * 12 * 3, 256, 0, stream>>>(Q, K, VT, ATT);
  convert2_kernel<<<288, 256, 0, stream>>>(proj_w, Wp);
  proj_kernel<<<1152, 256, 0, stream>>>(ATT, Wp, proj_b, out);
}

// Round 9
// 270.271 us; speedup vs baseline: 1.4433x; 1.0976x over previous
//
#include <hip/hip_runtime.h>

typedef __bf16 bf16;
typedef __bf16 bf16x4 __attribute__((ext_vector_type(4)));
typedef __bf16 bf16x8 __attribute__((ext_vector_type(8)));
typedef float f32x4 __attribute__((ext_vector_type(4)));

#define MFMA16(a,b,c) __builtin_amdgcn_mfma_f32_16x16x32_bf16((a),(b),(c),0,0,0)
#define SBAR() __builtin_amdgcn_s_barrier()
#define SCHED0() __builtin_amdgcn_sched_barrier(0)

// Shapes (fixed): B=32, N=384, C=768, H=12, Dh=64, mt=128, 2B=64 batches.
// Global inputs/outputs FLOAT32; intermediates bf16.
// Xb (x bf16 [24576][768]) + Wq (qkv_w bf16 [2304][768]) live in d_out scratch.
// ws: Q | K | VT | ATT (each 36 MB bf16) = 151 MB; Wp reuses Q after attn.
// V stored TRANSPOSED (VT[b'][h][d][tok]) by the qkv epilogue.
//
// attn (r9): swapped QK^T (St = K·Q^T) -> softmax reduction axis is
// lane-local (lane holds 32 keys for one q). Shuffles 64->16/chunk; P write
// becomes 16x ds_write_b64 (was 64 scalar b16, 4-way conflicted).

__device__ inline void gload16(const bf16* g, bf16* l) {
  __builtin_amdgcn_global_load_lds(
      (const __attribute__((address_space(1))) void*)g,
      (__attribute__((address_space(3))) void*)l, 16, 0, 0);
}

__device__ inline void stage128(const bf16* __restrict__ gsrc,
                                bf16* lds_base, int tid, int wv) {
#pragma unroll
  for (int r = 0; r < 4; ++r) {
    int s = r * 256 + tid;                        // 0..1023
    int row = s >> 3;
    int chunk = (s & 7) ^ (row & 7);
    gload16(gsrc + (size_t)row * 768 + chunk * 8,
            lds_base + (size_t)(r * 256 + wv * 64) * 8);
  }
}

__device__ inline bf16x8 frag64(const bf16* buf, int row, int ks, int lg) {
  int slot = ((ks << 2) | lg) ^ (row & 7);
  return *(const bf16x8*)(buf + (size_t)row * 64 + slot * 8);
}

// Counted-vmcnt K-loop over NTILES tiles of BK=64 (as r8, verified).
#define GEMM128_LOOP(APANEL, BPANEL, NTILES)                                    \
  do {                                                                          \
    stage128((APANEL), &As[0][0][0], tid, wv);                                  \
    stage128((BPANEL), &Bs[0][0][0], tid, wv);                                  \
    stage128((APANEL) + 64, &As[1][0][0], tid, wv);                             \
    stage128((BPANEL) + 64, &Bs[1][0][0], tid, wv);                             \
    asm volatile("s_waitcnt vmcnt(8)" ::: "memory"); SCHED0();                  \
    SBAR();                                                                     \
    int c = 0;                                                                  \
    for (int t = 0; t < (NTILES); ++t) {                                        \
      const bf16* Ab = &As[c][0][0];                                            \
      const bf16* Bb = &Bs[c][0][0];                                            \
      bf16x8 af[4][2], bfr[4][2];                                               \
      _Pragma("unroll")                                                         \
      for (int nf = 0; nf < 4; ++nf)                                            \
        _Pragma("unroll")                                                       \
        for (int ks = 0; ks < 2; ++ks)                                          \
          bfr[nf][ks] = frag64(Bb, wc + nf * 16 + lr, ks, lg);                  \
      _Pragma("unroll")                                                         \
      for (int mf = 0; mf < 4; ++mf)                                            \
        _Pragma("unroll")                                                       \
        for (int ks = 0; ks < 2; ++ks)                                          \
          af[mf][ks] = frag64(Ab, wr + mf * 16 + lr, ks, lg);                   \
      asm volatile("s_waitcnt lgkmcnt(0)" ::: "memory"); SCHED0();              \
      SBAR();   /* all waves done reading buf[c] -> safe to refill */           \
      if (t + 2 < (NTILES)) {                                                   \
        stage128((APANEL) + (t + 2) * 64, &As[c][0][0], tid, wv);               \
        stage128((BPANEL) + (t + 2) * 64, &Bs[c][0][0], tid, wv);               \
      }                                                                         \
      __builtin_amdgcn_s_setprio(1);                                            \
      _Pragma("unroll")                                                         \
      for (int mf = 0; mf < 4; ++mf)                                            \
        _Pragma("unroll")                                                       \
        for (int nf = 0; nf < 4; ++nf)                                          \
          _Pragma("unroll")                                                     \
          for (int ks = 0; ks < 2; ++ks)                                        \
            acc[mf][nf] = MFMA16(af[mf][ks], bfr[nf][ks], acc[mf][nf]);         \
      __builtin_amdgcn_s_setprio(0);                                            \
      if (t + 2 < (NTILES)) { asm volatile("s_waitcnt vmcnt(8)" ::: "memory"); }\
      else                  { asm volatile("s_waitcnt vmcnt(0)" ::: "memory"); }\
      SCHED0();                                                                 \
      SBAR();   /* buf[c^1] (tile t+1) now globally ready */                    \
      c ^= 1;                                                                   \
    }                                                                           \
  } while (0)

// ---------------------------------------------------------------------------
__global__ __launch_bounds__(256) void convert1_kernel(
    const float* __restrict__ xv, const float* __restrict__ xi,
    const float* __restrict__ w, bf16* __restrict__ dst)
{
  const size_t NV = 9437184;     // 12288*768
  const size_t NX = 18874368;    // 2*NV
  const size_t NT = 20643840;    // NX + 1769472 (qkv_w)
  for (size_t i = (size_t)blockIdx.x * 256 + threadIdx.x; i * 8 < NT;
       i += (size_t)gridDim.x * 256) {
    size_t e = i * 8;
    const float* src;
    if (e < NV)      src = xv + e;
    else if (e < NX) src = xi + (e - NV);
    else             src = w + (e - NX);
    f32x4 a = *(const f32x4*)src;
    f32x4 b = *(const f32x4*)(src + 4);
    bf16x8 r;
    r[0] = (bf16)a[0]; r[1] = (bf16)a[1]; r[2] = (bf16)a[2]; r[3] = (bf16)a[3];
    r[4] = (bf16)b[0]; r[5] = (bf16)b[1]; r[6] = (bf16)b[2]; r[7] = (bf16)b[3];
    *(bf16x8*)(dst + e) = r;
  }
}

__global__ __launch_bounds__(256) void convert2_kernel(
    const float* __restrict__ w, bf16* __restrict__ dst)
{
  size_t i = (size_t)blockIdx.x * 256 + threadIdx.x;
  size_t e = i * 8;
  if (e >= 589824) return;
  f32x4 a = *(const f32x4*)(w + e);
  f32x4 b = *(const f32x4*)(w + e + 4);
  bf16x8 r;
  r[0] = (bf16)a[0]; r[1] = (bf16)a[1]; r[2] = (bf16)a[2]; r[3] = (bf16)a[3];
  r[4] = (bf16)b[0]; r[5] = (bf16)b[1]; r[6] = (bf16)b[2]; r[7] = (bf16)b[3];
  *(bf16x8*)(dst + e) = r;
}

// ---------------------------------------------------------------------------
// Kernel 1: QKV projection. 128x128 tile, BK=64. Scatter epilogue: Q scaled,
// K row-major, V transposed (VT[b'][h][d][tok], 4 tok packed per 8B store).
// ---------------------------------------------------------------------------
__global__ __launch_bounds__(256, 2) void qkv_kernel(
    const bf16* __restrict__ X, const bf16* __restrict__ W,
    bf16* __restrict__ Qo, bf16* __restrict__ Ko, bf16* __restrict__ VTo)
{
  __shared__ bf16 As[2][128][64];
  __shared__ bf16 Bs[2][128][64];
  int bid = blockIdx.x;                    // 3456 blocks
  int swz = (bid & 7) * 432 + (bid >> 3);  // XCD-contiguous, bijective
  const int nt = swz % 18, mt = swz / 18;
  const int m0 = mt * 128, n0 = nt * 128;
  const int tid = threadIdx.x;
  const int lane = tid & 63;
  const int wv = tid >> 6;                 // 0..3
  const int wr = (wv >> 1) * 64, wc = (wv & 1) * 64;
  const int lr = lane & 15, lg = lane >> 4;

  const bf16* Xp = X + (size_t)m0 * 768;
  const bf16* Wp = W + (size_t)n0 * 768;

  f32x4 acc[4][4] = {};

  GEMM128_LOOP(Xp, Wp, 12);

#pragma unroll
  for (int mf = 0; mf < 4; ++mf)
#pragma unroll
    for (int nf = 0; nf < 4; ++nf) {
      int m = m0 + wr + mf * 16 + lg * 4;       // 4-aligned token base
      int n = n0 + wc + nf * 16 + lr;
      int bp = m / 384, tok = m - bp * 384;
      int comp = (n >= 1536) ? 2 : (n >= 768) ? 1 : 0;
      int rem = n - comp * 768;
      int hh = rem >> 6, d = rem & 63;
      if (comp == 2) {
        bf16x4 pk;
        pk[0] = (bf16)acc[mf][nf][0]; pk[1] = (bf16)acc[mf][nf][1];
        pk[2] = (bf16)acc[mf][nf][2]; pk[3] = (bf16)acc[mf][nf][3];
        *(bf16x4*)(VTo + (((size_t)bp * 12 + hh) * 64 + d) * 384 + tok) = pk;
      } else {
#pragma unroll
        for (int r = 0; r < 4; ++r) {
          size_t addr = (((size_t)bp * 12 + hh) * 384 + tok + r) * 64 + d;
          float val = acc[mf][nf][r];
          if (comp == 0) Qo[addr] = (bf16)(val * 0.125f);  // fold 1/sqrt(Dh)
          else           Ko[addr] = (bf16)val;
        }
      }
    }
}

// ---------------------------------------------------------------------------
// Kernel 2: attention, swapped-QK^T lane-local softmax. grid = 64*12*3.
// ---------------------------------------------------------------------------
__global__ __launch_bounds__(256) void attn_kernel(
    const bf16* __restrict__ Q, const bf16* __restrict__ K, const bf16* __restrict__ VT,
    bf16* __restrict__ ATT)
{
  __shared__ union {
    bf16 Qs[128][72];
    bf16 Ps[4][32][136];     // per-wave P tile [q_local][key] (Qs dead after qf cache)
  } u;
  __shared__ bf16 Ks[128][72];
  __shared__ bf16 VTs[64][136];     // transposed V: [d][token]

  const int bid = blockIdx.x;
  const int qb = bid % 3;
  const int h  = (bid / 3) % 12;
  const int bp = bid / 36;           // b' in [0,64)
  const int tid = threadIdx.x;
  const int lane = tid & 63;
  const int wv = tid >> 6;
  const int lr = lane & 15, lg = lane >> 4;

  const size_t bh384 = ((size_t)bp * 12 + h) * 384;
  const int q0 = qb * 128;

  for (int v = tid; v < 1024; v += 256) {
    int row = v >> 3, cg = (v & 7) * 8;
    *(bf16x8*)(&u.Qs[row][cg]) = *(const bf16x8*)(Q + (bh384 + q0 + row) * 64 + cg);
  }
  __syncthreads();

  bf16x8 qf[2][2];
#pragma unroll
  for (int mf = 0; mf < 2; ++mf)
#pragma unroll
    for (int ks = 0; ks < 2; ++ks)
      qf[mf][ks] = *(const bf16x8*)(&u.Qs[wv * 32 + mf * 16 + lr][ks * 32 + lg * 8]);

  f32x4 O[2][4] = {};
  // softmax state for q = mf*16 + lr (lane-local q)
  float runmax[2] = {-1e30f, -1e30f}, runsum[2] = {0.f, 0.f};

  const int nchunks = (qb == 0) ? 1 : 4;
  for (int c = 0; c < nchunks; ++c) {
    int src_b, t0;
    if (qb == 0)      { src_b = bp;            t0 = 0; }          // own mt
    else if (c == 0)  { src_b = bp & 31;       t0 = 0; }          // mt of V batch
    else if (c == 1)  { src_b = (bp & 31)+32;  t0 = 0; }          // mt of I batch
    else              { src_b = bp;            t0 = (c - 1) * 128; } // own s tokens
    const size_t kb  = (((size_t)src_b * 12 + h) * 384 + t0) * 64;
    const size_t vtb = ((size_t)src_b * 12 + h) * 64 * 384 + t0;

    __syncthreads();   // previous chunk fully consumed before restaging
    for (int v = tid; v < 1024; v += 256) {
      int row = v >> 3, cg = (v & 7) * 8;
      *(bf16x8*)(&Ks[row][cg]) = *(const bf16x8*)(K + kb + row * 64 + cg);
    }
    for (int v = tid; v < 1024; v += 256) {
      int d = v >> 4, p = (v & 15) * 8;
      *(bf16x8*)(&VTs[d][p]) = *(const bf16x8*)(VT + vtb + (size_t)d * 384 + p);
    }
    __syncthreads();

    // St = K * Q^T (swapped): lane holds St[key = nf*16+lg*4+r][q = mf*16+lr]
    f32x4 St[2][8] = {};
#pragma unroll
    for (int nf = 0; nf < 8; ++nf) {
#pragma unroll
      for (int ks = 0; ks < 2; ++ks) {
        bf16x8 kf = *(const bf16x8*)(&Ks[nf * 16 + lr][ks * 32 + lg * 8]);
        St[0][nf] = MFMA16(kf, qf[0][ks], St[0][nf]);
        St[1][nf] = MFMA16(kf, qf[1][ks], St[1][nf]);
      }
    }

    // online softmax: keys lane-local (32/lane) + 2 shfl to span 4 lg groups
    float rfq[2];
#pragma unroll
    for (int mf = 0; mf < 2; ++mf) {
      float mx = St[mf][0][0];
#pragma unroll
      for (int nf = 0; nf < 8; ++nf)
#pragma unroll
        for (int r = 0; r < 4; ++r) mx = fmaxf(mx, St[mf][nf][r]);
      mx = fmaxf(mx, __shfl_xor(mx, 16));
      mx = fmaxf(mx, __shfl_xor(mx, 32));
      float nm = fmaxf(runmax[mf], mx);
      rfq[mf] = __expf(runmax[mf] - nm);
      runmax[mf] = nm;
      float rs = 0.f;
#pragma unroll
      for (int nf = 0; nf < 8; ++nf)
#pragma unroll
        for (int r = 0; r < 4; ++r) {
          float p = __expf(St[mf][nf][r] - nm);
          St[mf][nf][r] = p;
          rs += p;
        }
      rs += __shfl_xor(rs, 16);
      rs += __shfl_xor(rs, 32);
      runsum[mf] = runsum[mf] * rfq[mf] + rs;
    }

    // P write: lane holds 4 consecutive keys per (mf,nf) -> packed b64 store
#pragma unroll
    for (int mf = 0; mf < 2; ++mf)
#pragma unroll
      for (int nf = 0; nf < 8; ++nf) {
        bf16x4 pk;
        pk[0] = (bf16)St[mf][nf][0]; pk[1] = (bf16)St[mf][nf][1];
        pk[2] = (bf16)St[mf][nf][2]; pk[3] = (bf16)St[mf][nf][3];
        *(bf16x4*)(&u.Ps[wv][mf * 16 + lr][nf * 16 + lg * 4]) = pk;
      }

    // O rescale: O-row q' = mf*16 + lg*4 + r -> pull rf from lane lr'=lg*4+r
#pragma unroll
    for (int mf = 0; mf < 2; ++mf)
#pragma unroll
      for (int r = 0; r < 4; ++r) {
        float rr = __shfl(rfq[mf], (lg * 4 + r) + (lg << 4));
#pragma unroll
        for (int vn = 0; vn < 4; ++vn) O[mf][vn][r] *= rr;
      }

#pragma unroll
    for (int ks = 0; ks < 4; ++ks) {
      bf16x8 pf0 = *(const bf16x8*)(&u.Ps[wv][lr][ks * 32 + lg * 8]);
      bf16x8 pf1 = *(const bf16x8*)(&u.Ps[wv][16 + lr][ks * 32 + lg * 8]);
#pragma unroll
      for (int vn = 0; vn < 4; ++vn) {
        bf16x8 vf = *(const bf16x8*)(&VTs[vn * 16 + lr][ks * 32 + lg * 8]);
        O[0][vn] = MFMA16(pf0, vf, O[0][vn]);
        O[1][vn] = MFMA16(pf1, vf, O[1][vn]);
      }
    }
  }

  // epilogue: divide by runsum of O-row q' (pull from lane lr' = lg*4+r)
#pragma unroll
  for (int mf = 0; mf < 2; ++mf) {
#pragma unroll
    for (int r = 0; r < 4; ++r) {
      float rs = __shfl(runsum[mf], (lg * 4 + r) + (lg << 4));
      float inv = 1.0f / rs;
#pragma unroll
      for (int vn = 0; vn < 4; ++vn) {
        int tok = q0 + wv * 32 + mf * 16 + lg * 4 + r;
        int d = vn * 16 + lr;
        ATT[((size_t)bp * 384 + tok) * 768 + h * 64 + d] = (bf16)(O[mf][vn][r] * inv);
      }
    }
  }
}

// ---------------------------------------------------------------------------
// Kernel 3: output projection. 128x128 tile, BK=64, f32 out + bias.
// ---------------------------------------------------------------------------
__global__ __launch_bounds__(256, 2) void proj_kernel(
    const bf16* __restrict__ A, const bf16* __restrict__ W,
    const float* __restrict__ bias, float* __restrict__ out)
{
  __shared__ bf16 As[2][128][64];
  __shared__ bf16 Bs[2][128][64];
  int bid = blockIdx.x;                    // 1152 blocks
  int swz = (bid & 7) * 144 + (bid >> 3);  // 1152 = 8*144
  const int nt = swz % 6, mt = swz / 6;
  const int m0 = mt * 128, n0 = nt * 128;
  const int tid = threadIdx.x;
  const int lane = tid & 63;
  const int wv = tid >> 6;
  const int wr = (wv >> 1) * 64, wc = (wv & 1) * 64;
  const int lr = lane & 15, lg = lane >> 4;

  const bf16* Ap = A + (size_t)m0 * 768;
  const bf16* Wpp = W + (size_t)n0 * 768;

  f32x4 acc[4][4] = {};

  GEMM128_LOOP(Ap, Wpp, 12);

#pragma unroll
  for (int mf = 0; mf < 4; ++mf)
#pragma unroll
    for (int nf = 0; nf < 4; ++nf)
#pragma unroll
      for (int r = 0; r < 4; ++r) {
        int m = m0 + wr + mf * 16 + lg * 4 + r;
        int n = n0 + wc + nf * 16 + lr;
        out[(size_t)m * 768 + n] = acc[mf][nf][r] + bias[n];
      }
}

// ---------------------------------------------------------------------------
extern "C" void kernel_launch(void* const* d_in, const int* in_sizes, int n_in,
                              void* d_out, int out_size, void* d_ws, size_t ws_size,
                              hipStream_t stream) {
  (void)in_sizes; (void)n_in; (void)out_size; (void)ws_size;
  const float* xv     = (const float*)d_in[0];
  const float* xi     = (const float*)d_in[1];
  const float* qkv_w  = (const float*)d_in[2];
  const float* proj_w = (const float*)d_in[3];
  const float* proj_b = (const float*)d_in[4];
  float* out = (float*)d_out;

  // bf16 scratch inside d_out (75.5 MB): Xb [24576][768] then Wq [2304][768].
  bf16* Xb = (bf16*)d_out;
  bf16* Wq = Xb + (size_t)18874368;

  // ws: Q | K | VT | ATT, each 18874368 bf16 (~36 MB) = 151 MB total.
  const size_t SZ = (size_t)64 * 12 * 384 * 64;
  bf16* Q   = (bf16*)d_ws;
  bf16* K   = Q + SZ;
  bf16* VT  = K + SZ;
  bf16* ATT = VT + SZ;
  bf16* Wp  = Q;                 // proj_w bf16, reuses Q region after attn

  convert1_kernel<<<2048, 256, 0, stream>>>(xv, xi, qkv_w, Xb);
  qkv_kernel<<<3456, 256, 0, stream>>>(Xb, Wq, Q, K, VT);
  attn_kernel<<<64 * 12 * 3, 256, 0, stream>>>(Q, K, VT, ATT);
  convert2_kernel<<<288, 256, 0, stream>>>(proj_w, Wp);
  proj_kernel<<<1152, 256, 0, stream>>>(ATT, Wp, proj_b, out);
}